// Round 1
// baseline (1219.023 us; speedup 1.0000x reference)
//
#include <hip/hip_runtime.h>

// SAGE-style mean aggregator + shared linear, fused.
// N=50000, S=25, D=128, OUT=128, K=2D=256.
// out[0 : N*128)          = (src ++ mean(src_neg)) @ w
// out[N*128 : 2*N*128)    = (dst ++ mean(dst_neg)) @ w

#define N_ROWS 50000
#define S_NEG  25
#define D_FEAT 128
#define OUT_F  128
#define K_TOT  256
#define RPB    32      // rows per block
#define KC     64      // k-chunk staged in LDS

__global__ __launch_bounds__(256, 2)
void sage_fused(const float* __restrict__ src,
                const float* __restrict__ src_neg,
                const float* __restrict__ dst,
                const float* __restrict__ dst_neg,
                const float* __restrict__ w,
                float* __restrict__ out) {
    __shared__ float s_cat[RPB][K_TOT];   // 32 KB: [r][0:128)=self, [128:256)=agg
    __shared__ float s_w[KC][OUT_F];      // 32 KB: current w k-chunk

    const int tid  = threadIdx.x;
    const int side = blockIdx.y;
    const int n0   = blockIdx.x * RPB;

    const float* selfp = side ? dst     : src;
    const float* negp  = side ? dst_neg : src_neg;
    float* outp = out + (size_t)side * (size_t)N_ROWS * OUT_F;

    // ---- Phase 1a: self features -> s_cat[r][0:128) ----
    #pragma unroll
    for (int i = 0; i < 4; ++i) {
        const int item = i * 256 + tid;     // 0..1023 = 32 rows x 32 float4s
        const int r  = item >> 5;
        const int dq = item & 31;
        const int n  = n0 + r;
        if (n < N_ROWS) {
            const float4 v = *(const float4*)(selfp + (size_t)n * D_FEAT + dq * 4);
            *(float4*)(&s_cat[r][dq * 4]) = v;
        }
    }

    // ---- Phase 1b: neighbor mean -> s_cat[r][128:256) ----
    #pragma unroll
    for (int i = 0; i < 4; ++i) {
        const int item = i * 256 + tid;
        const int r  = item >> 5;
        const int dq = item & 31;
        const int n  = n0 + r;
        if (n < N_ROWS) {
            const float* p = negp + (size_t)n * (S_NEG * D_FEAT) + dq * 4;
            float4 acc = {0.f, 0.f, 0.f, 0.f};
            #pragma unroll
            for (int s = 0; s < S_NEG; ++s) {
                const float4 v = *(const float4*)(p + s * D_FEAT);
                acc.x += v.x; acc.y += v.y; acc.z += v.z; acc.w += v.w;
            }
            const float inv = 1.0f / (float)S_NEG;
            acc.x *= inv; acc.y *= inv; acc.z *= inv; acc.w *= inv;
            *(float4*)(&s_cat[r][D_FEAT + dq * 4]) = acc;
        }
    }

    // ---- Phase 2: [32 x 256] @ [256 x 128] from LDS ----
    const int og = tid & 31;      // output quad index: outs [og*4, og*4+4)
    const int rg = tid >> 5;      // row group: rows [rg*4, rg*4+4)
    const int o0 = og * 4;

    float acc[4][4];
    #pragma unroll
    for (int a = 0; a < 4; ++a)
        #pragma unroll
        for (int b = 0; b < 4; ++b) acc[a][b] = 0.f;

    for (int c = 0; c < K_TOT / KC; ++c) {
        // barrier: (c==0) s_cat writes visible; (c>0) previous s_w reads done
        __syncthreads();

        // stage w chunk: KC*OUT_F = 8192 floats = 2048 float4 -> 8 per thread
        const float* wc = w + (size_t)c * KC * OUT_F;
        #pragma unroll
        for (int i = 0; i < 8; ++i) {
            const int item = i * 256 + tid;
            const float4 v = *(const float4*)(wc + (size_t)item * 4);
            *(float4*)(&((float*)s_w)[item * 4]) = v;
        }
        __syncthreads();

        const int kb = c * KC;
        #pragma unroll 4
        for (int kk = 0; kk < KC; kk += 4) {
            float4 cv[4];
            #pragma unroll
            for (int rr = 0; rr < 4; ++rr)
                cv[rr] = *(const float4*)(&s_cat[rg * 4 + rr][kb + kk]);
            #pragma unroll
            for (int j = 0; j < 4; ++j) {
                const float4 wv = *(const float4*)(&s_w[kk + j][o0]);
                #pragma unroll
                for (int rr = 0; rr < 4; ++rr) {
                    const float cval = (j == 0) ? cv[rr].x
                                     : (j == 1) ? cv[rr].y
                                     : (j == 2) ? cv[rr].z
                                                : cv[rr].w;
                    acc[rr][0] += cval * wv.x;
                    acc[rr][1] += cval * wv.y;
                    acc[rr][2] += cval * wv.z;
                    acc[rr][3] += cval * wv.w;
                }
            }
        }
    }

    // ---- Epilogue ----
    #pragma unroll
    for (int rr = 0; rr < 4; ++rr) {
        const int n = n0 + rg * 4 + rr;
        if (n < N_ROWS) {
            const float4 v = {acc[rr][0], acc[rr][1], acc[rr][2], acc[rr][3]};
            *(float4*)(outp + (size_t)n * OUT_F + o0) = v;
        }
    }
}

extern "C" void kernel_launch(void* const* d_in, const int* in_sizes, int n_in,
                              void* d_out, int out_size, void* d_ws, size_t ws_size,
                              hipStream_t stream) {
    const float* src     = (const float*)d_in[0];
    const float* src_neg = (const float*)d_in[1];
    const float* dst     = (const float*)d_in[2];
    const float* dst_neg = (const float*)d_in[3];
    const float* w       = (const float*)d_in[4];
    float* out = (float*)d_out;

    dim3 grid((N_ROWS + RPB - 1) / RPB, 2);
    dim3 block(256);
    sage_fused<<<grid, block, 0, stream>>>(src, src_neg, dst, dst_neg, w, out);
}